// Round 7
// baseline (680.847 us; speedup 1.0000x reference)
//
#include <hip/hip_runtime.h>
#include <hip/hip_bf16.h>
#include <stdint.h>

#define D_IN 128
#define D_H 256
#define NLAYERS 5

typedef __bf16 bf16x8 __attribute__((ext_vector_type(8)));
typedef __bf16 bf16x4 __attribute__((ext_vector_type(4)));
typedef float f32x4 __attribute__((ext_vector_type(4)));
typedef unsigned short u16x8 __attribute__((ext_vector_type(8)));

// LDS tile row stride in ushorts: 260 u16 = 520 B = 130 dwords; 130%32==2 so
// 16 consecutive rows at one column cover all 32 banks (measured 0 conflicts).
#define MID_STRIDE 260

__device__ inline __bf16 f2bf(float f) {
  __hip_bfloat16 h = __float2bfloat16(f);
  __bf16 r;
  __builtin_memcpy(&r, &h, sizeof(r));
  return r;
}

__device__ inline unsigned short bfbits(float f) {
  __hip_bfloat16 h = __float2bfloat16(f);
  unsigned short s;
  __builtin_memcpy(&s, &h, 2);
  return s;
}

__device__ inline float bf2f(unsigned short u) {
  return __uint_as_float((unsigned)u << 16);
}

// convert all 4 weight tensors to bf16 in one launch
__global__ void conv_weights(const float* __restrict__ a, const float* __restrict__ b,
                             const float* __restrict__ c, const float* __restrict__ d,
                             __hip_bfloat16* __restrict__ out) {
  int gid = blockIdx.x * blockDim.x + threadIdx.x;
  if (gid >= 622592) return;
  float v;
  if (gid < 32768) v = a[gid];
  else if (gid < 98304) v = b[gid - 32768];
  else if (gid < 360448) v = c[gid - 98304];
  else v = d[gid - 360448];
  out[gid] = __float2bfloat16(v);
}

__global__ void zero_ints(int* __restrict__ p, int n) {
  int i = blockIdx.x * blockDim.x + threadIdx.x;
  if (i < n) p[i] = 0;
}

// ---- CSR build ----
__global__ void hist_kernel(const int* __restrict__ ei, int E, int* __restrict__ deg) {
  int e = blockIdx.x * blockDim.x + threadIdx.x;
  if (e < E) atomicAdd(&deg[ei[E + e]], 1);
}

__global__ __launch_bounds__(256) void block_sums(const int* __restrict__ deg,
                                                  int* __restrict__ bsum, int N) {
  int t = threadIdx.x;
  int idx = blockIdx.x * 1024 + t * 4;
  int4 v = {0, 0, 0, 0};
  if (idx + 3 < N) v = *reinterpret_cast<const int4*>(deg + idx);
  else {
    if (idx + 0 < N) v.x = deg[idx + 0];
    if (idx + 1 < N) v.y = deg[idx + 1];
    if (idx + 2 < N) v.z = deg[idx + 2];
    if (idx + 3 < N) v.w = deg[idx + 3];
  }
  int s = v.x + v.y + v.z + v.w;
#pragma unroll
  for (int off = 32; off > 0; off >>= 1) s += __shfl_down(s, off);
  __shared__ int ws[4];
  int lane = t & 63, w = t >> 6;
  if (lane == 0) ws[w] = s;
  __syncthreads();
  if (t == 0) bsum[blockIdx.x] = ws[0] + ws[1] + ws[2] + ws[3];
}

__global__ void scan_bsums(int* __restrict__ bsum, int nb) {
  int t = threadIdx.x;
  int orig = (t < nb) ? bsum[t] : 0;
  int v = orig;
#pragma unroll
  for (int off = 1; off < 64; off <<= 1) {
    int u = __shfl_up(v, off);
    if (t >= off) v += u;
  }
  if (t < nb) bsum[t] = v - orig;  // exclusive
}

__global__ __launch_bounds__(256) void scan_apply(const int* __restrict__ deg,
                                                  const int* __restrict__ bsum_ex,
                                                  int* __restrict__ row_start, int N) {
  int t = threadIdx.x;
  int idx = blockIdx.x * 1024 + t * 4;
  int4 v = {0, 0, 0, 0};
  if (idx + 3 < N) v = *reinterpret_cast<const int4*>(deg + idx);
  else {
    if (idx + 0 < N) v.x = deg[idx + 0];
    if (idx + 1 < N) v.y = deg[idx + 1];
    if (idx + 2 < N) v.z = deg[idx + 2];
    if (idx + 3 < N) v.w = deg[idx + 3];
  }
  int s = v.x + v.y + v.z + v.w;
  int lane = t & 63, w = t >> 6;
  int sc = s;
#pragma unroll
  for (int off = 1; off < 64; off <<= 1) {
    int u = __shfl_up(sc, off);
    if (lane >= off) sc += u;
  }
  __shared__ int woff[4];
  if (lane == 63) woff[w] = sc;
  __syncthreads();
  int boff = bsum_ex[blockIdx.x];
#pragma unroll
  for (int i = 0; i < 4; ++i)
    if (i < w) boff += woff[i];
  int ex = boff + sc - s;
  if (idx + 3 < N) {
    int4 o;
    o.x = ex;
    o.y = ex + v.x;
    o.z = ex + v.x + v.y;
    o.w = ex + v.x + v.y + v.z;
    *reinterpret_cast<int4*>(row_start + idx) = o;
  } else {
    if (idx + 0 < N) row_start[idx + 0] = ex;
    if (idx + 1 < N) row_start[idx + 1] = ex + v.x;
    if (idx + 2 < N) row_start[idx + 2] = ex + v.x + v.y;
    if (idx + 3 < N) row_start[idx + 3] = ex + v.x + v.y + v.z;
  }
}

__global__ void fill_kernel(const int* __restrict__ ei, int E,
                            const int* __restrict__ row_start,
                            int* __restrict__ cursor, int* __restrict__ csr) {
  int e = blockIdx.x * blockDim.x + threadIdx.x;
  if (e >= E) return;
  int d = ei[E + e];
  int p = atomicAdd(&cursor[d], 1);
  csr[row_start[d] + p] = ei[e];
}

// ==== fully fused GIN layer ====
// out = relu( relu( ((1+eps)h + sum_nbr h) @ W0.T + b0 ) @ W1.T + b1 )
// NOTE: input and output node buffers MUST be distinct (cross-block RAW
// hazard otherwise — neighbors span all blocks). Caller double-buffers.
// Block = 256 thr (4 waves) = 64 nodes.
template <int K0, bool IN_F32, bool OUT_BF16>
__global__ __launch_bounds__(256) void gin_layer(
    const void* __restrict__ hin, const int* __restrict__ csr,
    const int* __restrict__ row_start, const int* __restrict__ deg,
    const float* __restrict__ eps_all, int layer,
    const __hip_bfloat16* __restrict__ W0, const float* __restrict__ b0,
    const __hip_bfloat16* __restrict__ W1, const float* __restrict__ b1,
    void* __restrict__ Outp, int N) {
  __shared__ unsigned short Abuf[64 * MID_STRIDE];  // 33.3 KB, reused for mid

  const int row0 = blockIdx.x * 64;

  // ---- Phase 1: aggregate into LDS ----
  {
    const int hw = threadIdx.x >> 5;    // 0..7
    const int l32 = threadIdx.x & 31;
    const float epsv = 1.0f + eps_all[layer];
#pragma unroll
    for (int it = 0; it < 8; ++it) {
      const int node_l = it * 8 + hw;
      const int node = row0 + node_l;
      if (IN_F32) {  // layer 0: K0=128, fp32 input rows
        f32x4 acc = 0.0f;
        if (node < N) {
          const float* hf = (const float*)hin;
          const int start = row_start[node];
          const int cnt = deg[node];
          for (int base = 0; base < cnt; base += 32) {
            int m = cnt - base;
            if (m > 32) m = 32;
            int idx = (l32 < m) ? csr[start + base + l32] : 0;
            int i = 0;
            for (; i + 4 <= m; i += 4) {
              int s0 = __shfl(idx, i + 0, 32);
              int s1 = __shfl(idx, i + 1, 32);
              int s2 = __shfl(idx, i + 2, 32);
              int s3 = __shfl(idx, i + 3, 32);
              f32x4 v0 = *reinterpret_cast<const f32x4*>(hf + (size_t)s0 * K0 + l32 * 4);
              f32x4 v1 = *reinterpret_cast<const f32x4*>(hf + (size_t)s1 * K0 + l32 * 4);
              f32x4 v2 = *reinterpret_cast<const f32x4*>(hf + (size_t)s2 * K0 + l32 * 4);
              f32x4 v3 = *reinterpret_cast<const f32x4*>(hf + (size_t)s3 * K0 + l32 * 4);
              acc += (v0 + v1) + (v2 + v3);
            }
            for (; i < m; ++i) {
              int s0 = __shfl(idx, i, 32);
              acc += *reinterpret_cast<const f32x4*>(hf + (size_t)s0 * K0 + l32 * 4);
            }
          }
          f32x4 self = *reinterpret_cast<const f32x4*>(
              (const float*)hin + (size_t)node * K0 + l32 * 4);
          acc += self * epsv;
        }
        ushort4 o;
        o.x = bfbits(acc[0]);
        o.y = bfbits(acc[1]);
        o.z = bfbits(acc[2]);
        o.w = bfbits(acc[3]);
        *reinterpret_cast<ushort4*>(Abuf + node_l * MID_STRIDE + l32 * 4) = o;
      } else {  // layers 1..4: K0=256, bf16 input rows
        float acc[8];
#pragma unroll
        for (int j = 0; j < 8; ++j) acc[j] = 0.0f;
        if (node < N) {
          const unsigned short* hb = (const unsigned short*)hin;
          const int start = row_start[node];
          const int cnt = deg[node];
          for (int base = 0; base < cnt; base += 32) {
            int m = cnt - base;
            if (m > 32) m = 32;
            int idx = (l32 < m) ? csr[start + base + l32] : 0;
            int i = 0;
            for (; i + 4 <= m; i += 4) {
              int s0 = __shfl(idx, i + 0, 32);
              int s1 = __shfl(idx, i + 1, 32);
              int s2 = __shfl(idx, i + 2, 32);
              int s3 = __shfl(idx, i + 3, 32);
              u16x8 u0 = *reinterpret_cast<const u16x8*>(hb + (size_t)s0 * K0 + l32 * 8);
              u16x8 u1 = *reinterpret_cast<const u16x8*>(hb + (size_t)s1 * K0 + l32 * 8);
              u16x8 u2 = *reinterpret_cast<const u16x8*>(hb + (size_t)s2 * K0 + l32 * 8);
              u16x8 u3 = *reinterpret_cast<const u16x8*>(hb + (size_t)s3 * K0 + l32 * 8);
#pragma unroll
              for (int j = 0; j < 8; ++j)
                acc[j] += (bf2f(u0[j]) + bf2f(u1[j])) + (bf2f(u2[j]) + bf2f(u3[j]));
            }
            for (; i < m; ++i) {
              int s0 = __shfl(idx, i, 32);
              u16x8 u0 = *reinterpret_cast<const u16x8*>(hb + (size_t)s0 * K0 + l32 * 8);
#pragma unroll
              for (int j = 0; j < 8; ++j) acc[j] += bf2f(u0[j]);
            }
          }
          u16x8 su = *reinterpret_cast<const u16x8*>(
              (const unsigned short*)hin + (size_t)node * K0 + l32 * 8);
#pragma unroll
          for (int j = 0; j < 8; ++j) acc[j] += epsv * bf2f(su[j]);
        }
        u16x8 o;
#pragma unroll
        for (int j = 0; j < 8; ++j) o[j] = bfbits(acc[j]);
        *reinterpret_cast<u16x8*>(Abuf + node_l * MID_STRIDE + l32 * 8) = o;
      }
    }
  }
  __syncthreads();

  // ---- Phase 2: GEMM0 (A from LDS) ----
  const int lane = threadIdx.x & 63;
  const int wave = threadIdx.x >> 6;  // 0..3
  const int l15 = lane & 15;
  const int kg = lane >> 4;  // 0..3
  const int col0 = wave * 64;

  const __hip_bfloat16* w0row[4];
#pragma unroll
  for (int ct = 0; ct < 4; ++ct)
    w0row[ct] = W0 + (size_t)(col0 + ct * 16 + l15) * K0 + kg * 8;

  f32x4 acc0[2][2][4];
#pragma unroll
  for (int t = 0; t < 2; ++t)
#pragma unroll
    for (int rt = 0; rt < 2; ++rt)
#pragma unroll
      for (int ct = 0; ct < 4; ++ct) acc0[t][rt][ct] = 0.0f;

#pragma unroll
  for (int kk = 0; kk < K0 / 32; ++kk) {
    const int off = kk * 32;
    bf16x8 bfr[4];
#pragma unroll
    for (int ct = 0; ct < 4; ++ct)
      bfr[ct] = *reinterpret_cast<const bf16x8*>(w0row[ct] + off);
    bf16x8 afr[2][2];
#pragma unroll
    for (int t = 0; t < 2; ++t)
#pragma unroll
      for (int rt = 0; rt < 2; ++rt) {
        const unsigned short* p =
            Abuf + (t * 32 + rt * 16 + l15) * MID_STRIDE + off + kg * 8;
        bf16x4 lo = *reinterpret_cast<const bf16x4*>(p);
        bf16x4 hi = *reinterpret_cast<const bf16x4*>(p + 4);
        bf16x8 a;
#pragma unroll
        for (int j = 0; j < 4; ++j) {
          a[j] = lo[j];
          a[j + 4] = hi[j];
        }
        afr[t][rt] = a;
      }
#pragma unroll
    for (int t = 0; t < 2; ++t)
#pragma unroll
      for (int rt = 0; rt < 2; ++rt)
#pragma unroll
        for (int ct = 0; ct < 4; ++ct)
          acc0[t][rt][ct] = __builtin_amdgcn_mfma_f32_16x16x32_bf16(
              afr[t][rt], bfr[ct], acc0[t][rt][ct], 0, 0, 0);
  }
  __syncthreads();  // all reads of Abuf done before overwrite

  // ---- Phase 3: epilogue0 -> LDS (mid = relu(. + b0), bf16) ----
#pragma unroll
  for (int t = 0; t < 2; ++t)
#pragma unroll
    for (int ct = 0; ct < 4; ++ct) {
      int col = col0 + ct * 16 + l15;
      float bv = b0[col];
#pragma unroll
      for (int rt = 0; rt < 2; ++rt)
#pragma unroll
        for (int i = 0; i < 4; ++i) {
          int row_l = t * 32 + rt * 16 + kg * 4 + i;
          Abuf[row_l * MID_STRIDE + col] =
              bfbits(fmaxf(acc0[t][rt][ct][i] + bv, 0.0f));
        }
    }
  __syncthreads();

  // ---- Phase 4: GEMM1 (A from LDS, K=256) ----
  const unsigned short* w1row[4];
#pragma unroll
  for (int ct = 0; ct < 4; ++ct)
    w1row[ct] =
        (const unsigned short*)W1 + (size_t)(col0 + ct * 16 + l15) * D_H + kg * 8;

  f32x4 acc1[2][2][4];
#pragma unroll
  for (int t = 0; t < 2; ++t)
#pragma unroll
    for (int rt = 0; rt < 2; ++rt)
#pragma unroll
      for (int ct = 0; ct < 4; ++ct) acc1[t][rt][ct] = 0.0f;

#pragma unroll
  for (int kk = 0; kk < D_H / 32; ++kk) {
    const int off = kk * 32;
    bf16x8 wfr[4];
#pragma unroll
    for (int ct = 0; ct < 4; ++ct)
      wfr[ct] = *reinterpret_cast<const bf16x8*>(w1row[ct] + off);
    bf16x8 afr[2][2];
#pragma unroll
    for (int t = 0; t < 2; ++t)
#pragma unroll
      for (int rt = 0; rt < 2; ++rt) {
        const unsigned short* p =
            Abuf + (t * 32 + rt * 16 + l15) * MID_STRIDE + off + kg * 8;
        bf16x4 lo = *reinterpret_cast<const bf16x4*>(p);
        bf16x4 hi = *reinterpret_cast<const bf16x4*>(p + 4);
        bf16x8 a;
#pragma unroll
        for (int j = 0; j < 4; ++j) {
          a[j] = lo[j];
          a[j + 4] = hi[j];
        }
        afr[t][rt] = a;
      }
#pragma unroll
    for (int t = 0; t < 2; ++t)
#pragma unroll
      for (int rt = 0; rt < 2; ++rt)
#pragma unroll
        for (int ct = 0; ct < 4; ++ct)
          acc1[t][rt][ct] = __builtin_amdgcn_mfma_f32_16x16x32_bf16(
              afr[t][rt], wfr[ct], acc1[t][rt][ct], 0, 0, 0);
  }

  // ---- epilogue1 -> global (relu) ----
#pragma unroll
  for (int t = 0; t < 2; ++t)
#pragma unroll
    for (int ct = 0; ct < 4; ++ct) {
      int col = col0 + ct * 16 + l15;
      float bv = b1[col];
#pragma unroll
      for (int rt = 0; rt < 2; ++rt)
#pragma unroll
        for (int i = 0; i < 4; ++i) {
          int row = row0 + t * 32 + rt * 16 + kg * 4 + i;
          if (row < N) {
            float v = fmaxf(acc1[t][rt][ct][i] + bv, 0.0f);
            if (OUT_BF16)
              ((__hip_bfloat16*)Outp)[(size_t)row * D_H + col] = __float2bfloat16(v);
            else
              ((float*)Outp)[(size_t)row * D_H + col] = v;
          }
        }
    }
}

extern "C" void kernel_launch(void* const* d_in, const int* in_sizes, int n_in,
                              void* d_out, int out_size, void* d_ws, size_t ws_size,
                              hipStream_t stream) {
  const float* x = (const float*)d_in[0];
  const int* ei = (const int*)d_in[1];  // [2, E]: row0 = src, row1 = dst
  const float* eps_all = (const float*)d_in[2];
  const float* w0_l0 = (const float*)d_in[3];
  const float* b0_l0 = (const float*)d_in[4];
  const float* w1_l0 = (const float*)d_in[5];
  const float* b1_l0 = (const float*)d_in[6];
  const float* w0_rest = (const float*)d_in[7];
  const float* b0_rest = (const float*)d_in[8];
  const float* w1_rest = (const float*)d_in[9];
  const float* b1_rest = (const float*)d_in[10];

  const int N = in_sizes[0] / D_IN;  // 50000
  const int E = in_sizes[1] / 2;     // 800000

  char* ws = (char*)d_ws;
  const size_t node_bf = (size_t)N * D_H * sizeof(unsigned short);  // 25.6 MB
  unsigned short* h0 = (unsigned short*)ws;              // ping
  unsigned short* h1 = (unsigned short*)(ws + node_bf);  // pong
  char* p = ws + 2 * node_bf;
  __hip_bfloat16* wbf = (__hip_bfloat16*)p;
  p += 622592 * sizeof(__hip_bfloat16);
  int* deg = (int*)p;           // [N]
  int* cursor = deg + N;        // [N]
  int* row_start = cursor + N;  // [N]
  int* bsum = row_start + N;    // [64]
  int* csr = bsum + 64;         // [E]

  __hip_bfloat16* w0_l0_bf = wbf;
  __hip_bfloat16* w1_l0_bf = wbf + 32768;
  __hip_bfloat16* w0_rest_bf = wbf + 98304;
  __hip_bfloat16* w1_rest_bf = w0_rest_bf + 262144;

  conv_weights<<<(622592 + 255) / 256, 256, 0, stream>>>(w0_l0, w1_l0, w0_rest,
                                                         w1_rest, wbf);

  // CSR build
  const int nb = (N + 1023) / 1024;  // 49
  zero_ints<<<(2 * N + 255) / 256, 256, 0, stream>>>(deg, 2 * N);  // deg + cursor
  hist_kernel<<<(E + 255) / 256, 256, 0, stream>>>(ei, E, deg);
  block_sums<<<nb, 256, 0, stream>>>(deg, bsum, N);
  scan_bsums<<<1, 64, 0, stream>>>(bsum, nb);
  scan_apply<<<nb, 256, 0, stream>>>(deg, bsum, row_start, N);
  fill_kernel<<<(E + 255) / 256, 256, 0, stream>>>(ei, E, row_start, cursor, csr);

  const int layerBlocks = (N + 63) / 64;

  // double-buffer node features: layer L reads buf[L%2], writes buf[(L+1)%2]
  unsigned short* hbuf[2] = {h0, h1};

  for (int layer = 0; layer < NLAYERS; ++layer) {
    const __hip_bfloat16* w0 =
        (layer == 0) ? w0_l0_bf : w0_rest_bf + (size_t)(layer - 1) * 65536;
    const float* b0 = (layer == 0) ? b0_l0 : b0_rest + (size_t)(layer - 1) * 256;
    const __hip_bfloat16* w1 =
        (layer == 0) ? w1_l0_bf : w1_rest_bf + (size_t)(layer - 1) * 65536;
    const float* b1 = (layer == 0) ? b1_l0 : b1_rest + (size_t)(layer - 1) * 256;

    if (layer == 0) {
      gin_layer<D_IN, true, true><<<layerBlocks, 256, 0, stream>>>(
          x, csr, row_start, deg, eps_all, layer, w0, b0, w1, b1, hbuf[1], N);
    } else if (layer == NLAYERS - 1) {
      gin_layer<D_H, false, false><<<layerBlocks, 256, 0, stream>>>(
          hbuf[layer % 2], csr, row_start, deg, eps_all, layer, w0, b0, w1, b1,
          d_out, N);
    } else {
      gin_layer<D_H, false, true><<<layerBlocks, 256, 0, stream>>>(
          hbuf[layer % 2], csr, row_start, deg, eps_all, layer, w0, b0, w1, b1,
          hbuf[(layer + 1) % 2], N);
    }
  }
}

// Round 8
// 626.554 us; speedup vs baseline: 1.0867x; 1.0867x over previous
//
#include <hip/hip_runtime.h>
#include <hip/hip_bf16.h>
#include <stdint.h>

#define D_IN 128
#define D_H 256
#define NLAYERS 5

typedef __bf16 bf16x8 __attribute__((ext_vector_type(8)));
typedef __bf16 bf16x4 __attribute__((ext_vector_type(4)));
typedef float f32x4 __attribute__((ext_vector_type(4)));
typedef unsigned short u16x8 __attribute__((ext_vector_type(8)));

// LDS tile row stride in ushorts: 260 u16 = 520 B = 130 dwords; 130%32==2 so
// 16 consecutive rows at one column cover all 32 banks (measured 0 conflicts).
#define MID_STRIDE 260

__device__ inline __bf16 f2bf(float f) {
  __hip_bfloat16 h = __float2bfloat16(f);
  __bf16 r;
  __builtin_memcpy(&r, &h, sizeof(r));
  return r;
}

__device__ inline unsigned short bfbits(float f) {
  __hip_bfloat16 h = __float2bfloat16(f);
  unsigned short s;
  __builtin_memcpy(&s, &h, 2);
  return s;
}

__device__ inline float bf2f(unsigned short u) {
  return __uint_as_float((unsigned)u << 16);
}

// convert all 4 weight tensors to bf16 in one launch
__global__ void conv_weights(const float* __restrict__ a, const float* __restrict__ b,
                             const float* __restrict__ c, const float* __restrict__ d,
                             __hip_bfloat16* __restrict__ out) {
  int gid = blockIdx.x * blockDim.x + threadIdx.x;
  if (gid >= 622592) return;
  float v;
  if (gid < 32768) v = a[gid];
  else if (gid < 98304) v = b[gid - 32768];
  else if (gid < 360448) v = c[gid - 98304];
  else v = d[gid - 360448];
  out[gid] = __float2bfloat16(v);
}

__global__ void zero_ints(int* __restrict__ p, int n) {
  int i = blockIdx.x * blockDim.x + threadIdx.x;
  if (i < n) p[i] = 0;
}

// ---- CSR build ----
__global__ void hist_kernel(const int* __restrict__ ei, int E, int* __restrict__ deg) {
  int e = blockIdx.x * blockDim.x + threadIdx.x;
  if (e < E) atomicAdd(&deg[ei[E + e]], 1);
}

__global__ __launch_bounds__(256) void block_sums(const int* __restrict__ deg,
                                                  int* __restrict__ bsum, int N) {
  int t = threadIdx.x;
  int idx = blockIdx.x * 1024 + t * 4;
  int4 v = {0, 0, 0, 0};
  if (idx + 3 < N) v = *reinterpret_cast<const int4*>(deg + idx);
  else {
    if (idx + 0 < N) v.x = deg[idx + 0];
    if (idx + 1 < N) v.y = deg[idx + 1];
    if (idx + 2 < N) v.z = deg[idx + 2];
    if (idx + 3 < N) v.w = deg[idx + 3];
  }
  int s = v.x + v.y + v.z + v.w;
#pragma unroll
  for (int off = 32; off > 0; off >>= 1) s += __shfl_down(s, off);
  __shared__ int ws[4];
  int lane = t & 63, w = t >> 6;
  if (lane == 0) ws[w] = s;
  __syncthreads();
  if (t == 0) bsum[blockIdx.x] = ws[0] + ws[1] + ws[2] + ws[3];
}

__global__ void scan_bsums(int* __restrict__ bsum, int nb) {
  int t = threadIdx.x;
  int orig = (t < nb) ? bsum[t] : 0;
  int v = orig;
#pragma unroll
  for (int off = 1; off < 64; off <<= 1) {
    int u = __shfl_up(v, off);
    if (t >= off) v += u;
  }
  if (t < nb) bsum[t] = v - orig;  // exclusive
}

__global__ __launch_bounds__(256) void scan_apply(const int* __restrict__ deg,
                                                  const int* __restrict__ bsum_ex,
                                                  int* __restrict__ row_start, int N) {
  int t = threadIdx.x;
  int idx = blockIdx.x * 1024 + t * 4;
  int4 v = {0, 0, 0, 0};
  if (idx + 3 < N) v = *reinterpret_cast<const int4*>(deg + idx);
  else {
    if (idx + 0 < N) v.x = deg[idx + 0];
    if (idx + 1 < N) v.y = deg[idx + 1];
    if (idx + 2 < N) v.z = deg[idx + 2];
    if (idx + 3 < N) v.w = deg[idx + 3];
  }
  int s = v.x + v.y + v.z + v.w;
  int lane = t & 63, w = t >> 6;
  int sc = s;
#pragma unroll
  for (int off = 1; off < 64; off <<= 1) {
    int u = __shfl_up(sc, off);
    if (lane >= off) sc += u;
  }
  __shared__ int woff[4];
  if (lane == 63) woff[w] = sc;
  __syncthreads();
  int boff = bsum_ex[blockIdx.x];
#pragma unroll
  for (int i = 0; i < 4; ++i)
    if (i < w) boff += woff[i];
  int ex = boff + sc - s;
  if (idx + 3 < N) {
    int4 o;
    o.x = ex;
    o.y = ex + v.x;
    o.z = ex + v.x + v.y;
    o.w = ex + v.x + v.y + v.z;
    *reinterpret_cast<int4*>(row_start + idx) = o;
  } else {
    if (idx + 0 < N) row_start[idx + 0] = ex;
    if (idx + 1 < N) row_start[idx + 1] = ex + v.x;
    if (idx + 2 < N) row_start[idx + 2] = ex + v.x + v.y;
    if (idx + 3 < N) row_start[idx + 3] = ex + v.x + v.y + v.z;
  }
}

__global__ void fill_kernel(const int* __restrict__ ei, int E,
                            const int* __restrict__ row_start,
                            int* __restrict__ cursor, int* __restrict__ csr) {
  int e = blockIdx.x * blockDim.x + threadIdx.x;
  if (e >= E) return;
  int d = ei[E + e];
  int p = atomicAdd(&cursor[d], 1);
  csr[row_start[d] + p] = ei[e];
}

// ---- fused aggregation: pre[n] = bf16( (1+eps)*h[n] + sum_{s in in(n)} h[s] ) ----
// half-wave (32 lanes) per node; lane holds 16 B of the row. Neighbor indices
// are preloaded 32-at-a-time (one coalesced load) and broadcast via shfl so
// the row loads have no index-load dependency; 4 rows in flight. Big grid
// (N/8 blocks) maximizes waves-in-flight — the gather is latency-bound.
template <int D, bool IN_F32>
__global__ __launch_bounds__(256) void aggregate(const void* __restrict__ hin,
                                                 const int* __restrict__ csr,
                                                 const int* __restrict__ row_start,
                                                 const int* __restrict__ deg,
                                                 const float* __restrict__ eps_all,
                                                 int layer,
                                                 unsigned short* __restrict__ pre,
                                                 int N) {
  const int half = threadIdx.x >> 5;  // 0..7
  const int lane = threadIdx.x & 31;
  const int node = blockIdx.x * 8 + half;
  if (node >= N) return;

  const int start = row_start[node];
  const int cnt = deg[node];

  if (IN_F32) {  // D=128 fp32: lane holds float4
    const float* hf = (const float*)hin;
    f32x4 self = *reinterpret_cast<const f32x4*>(hf + (size_t)node * D + lane * 4);
    f32x4 acc = 0.0f;
    for (int base = 0; base < cnt; base += 32) {
      int m = cnt - base;
      if (m > 32) m = 32;
      int idx = (lane < m) ? csr[start + base + lane] : 0;
      int i = 0;
      for (; i + 4 <= m; i += 4) {
        int s0 = __shfl(idx, i + 0, 32);
        int s1 = __shfl(idx, i + 1, 32);
        int s2 = __shfl(idx, i + 2, 32);
        int s3 = __shfl(idx, i + 3, 32);
        f32x4 v0 = *reinterpret_cast<const f32x4*>(hf + (size_t)s0 * D + lane * 4);
        f32x4 v1 = *reinterpret_cast<const f32x4*>(hf + (size_t)s1 * D + lane * 4);
        f32x4 v2 = *reinterpret_cast<const f32x4*>(hf + (size_t)s2 * D + lane * 4);
        f32x4 v3 = *reinterpret_cast<const f32x4*>(hf + (size_t)s3 * D + lane * 4);
        acc += (v0 + v1) + (v2 + v3);
      }
      for (; i < m; ++i) {
        int s0 = __shfl(idx, i, 32);
        acc += *reinterpret_cast<const f32x4*>(hf + (size_t)s0 * D + lane * 4);
      }
    }
    float epsv = 1.0f + eps_all[layer];
    acc += self * epsv;
    ushort4 o;
    o.x = bfbits(acc[0]);
    o.y = bfbits(acc[1]);
    o.z = bfbits(acc[2]);
    o.w = bfbits(acc[3]);
    *reinterpret_cast<ushort4*>(pre + (size_t)node * D + lane * 4) = o;
  } else {  // D=256 bf16: lane holds ushort8
    const unsigned short* hb = (const unsigned short*)hin;
    u16x8 su = *reinterpret_cast<const u16x8*>(hb + (size_t)node * D + lane * 8);
    float acc[8];
#pragma unroll
    for (int j = 0; j < 8; ++j) acc[j] = 0.0f;
    for (int base = 0; base < cnt; base += 32) {
      int m = cnt - base;
      if (m > 32) m = 32;
      int idx = (lane < m) ? csr[start + base + lane] : 0;
      int i = 0;
      for (; i + 4 <= m; i += 4) {
        int s0 = __shfl(idx, i + 0, 32);
        int s1 = __shfl(idx, i + 1, 32);
        int s2 = __shfl(idx, i + 2, 32);
        int s3 = __shfl(idx, i + 3, 32);
        u16x8 u0 = *reinterpret_cast<const u16x8*>(hb + (size_t)s0 * D + lane * 8);
        u16x8 u1 = *reinterpret_cast<const u16x8*>(hb + (size_t)s1 * D + lane * 8);
        u16x8 u2 = *reinterpret_cast<const u16x8*>(hb + (size_t)s2 * D + lane * 8);
        u16x8 u3 = *reinterpret_cast<const u16x8*>(hb + (size_t)s3 * D + lane * 8);
#pragma unroll
        for (int j = 0; j < 8; ++j)
          acc[j] += (bf2f(u0[j]) + bf2f(u1[j])) + (bf2f(u2[j]) + bf2f(u3[j]));
      }
      for (; i < m; ++i) {
        int s0 = __shfl(idx, i, 32);
        u16x8 u0 = *reinterpret_cast<const u16x8*>(hb + (size_t)s0 * D + lane * 8);
#pragma unroll
        for (int j = 0; j < 8; ++j) acc[j] += bf2f(u0[j]);
      }
    }
    float epsv = 1.0f + eps_all[layer];
    u16x8 o;
#pragma unroll
    for (int j = 0; j < 8; ++j) o[j] = bfbits(acc[j] + epsv * bf2f(su[j]));
    *reinterpret_cast<u16x8*>(pre + (size_t)node * D + lane * 8) = o;
  }
}

// ---- fused 2-layer MLP: out = relu( relu(A@W0.T+b0) @ W1.T + b1 ) ----
// Block = 256 thr (4 waves) = 64 rows x 256 cols.
// Phase 0: stage the 64xK0 A-tile into LDS (coalesced 16B/thread) so the
//          k-loop has zero global-A latency; W streams from L2 (hot).
// Phase 1: GEMM0 from LDS; wave owns 64 cols, T=2 row-tiles, W-frags reused
//          across tiles (16 MFMA : 4 L2-loads : 4 LDS-reads per k-step).
// Phase 2: epilogue0 overwrites the LDS tile with mid = relu(.+b0).
// Phase 3: GEMM1 from LDS -> global.
// mfma_f32_16x16x32_bf16 frag maps: A/B row/col = lane&15, k = (lane>>4)*8 + j;
// C/D: col = lane&15, row = (lane>>4)*4 + reg.
template <int K0, bool OUT_BF16>
__global__ __launch_bounds__(256) void gin_mlp(const __hip_bfloat16* __restrict__ Ap,
                                               const __hip_bfloat16* __restrict__ W0,
                                               const float* __restrict__ b0,
                                               const __hip_bfloat16* __restrict__ W1,
                                               const float* __restrict__ b1,
                                               void* __restrict__ Outp, int Nrows) {
  __shared__ unsigned short Abuf[64 * MID_STRIDE];  // 33.3 KB; A-tile then mid

  const int row0 = blockIdx.x * 64;

  // ---- Phase 0: stage A-tile into LDS ----
  {
    constexpr int CPR = K0 / 8;       // 16B chunks per row
    constexpr int TOT = 64 * CPR;
    const unsigned short* As = (const unsigned short*)Ap;
#pragma unroll
    for (int c = threadIdx.x; c < TOT; c += 256) {
      int row = c / CPR;
      int col = (c % CPR) * 8;
      int grow = row0 + row;
      if (grow > Nrows - 1) grow = Nrows - 1;  // clamp: dup rows only feed discarded C
      u16x8 v = *reinterpret_cast<const u16x8*>(As + (size_t)grow * K0 + col);
      *reinterpret_cast<u16x8*>(Abuf + row * MID_STRIDE + col) = v;
    }
  }
  __syncthreads();

  const int lane = threadIdx.x & 63;
  const int wave = threadIdx.x >> 6;  // 0..3
  const int l15 = lane & 15;
  const int kg = lane >> 4;  // 0..3
  const int col0 = wave * 64;

  // ---- Phase 1: GEMM0 (A from LDS, W from L2) ----
  const __hip_bfloat16* w0row[4];
#pragma unroll
  for (int ct = 0; ct < 4; ++ct)
    w0row[ct] = W0 + (size_t)(col0 + ct * 16 + l15) * K0 + kg * 8;

  f32x4 acc0[2][2][4];
#pragma unroll
  for (int t = 0; t < 2; ++t)
#pragma unroll
    for (int rt = 0; rt < 2; ++rt)
#pragma unroll
      for (int ct = 0; ct < 4; ++ct) acc0[t][rt][ct] = 0.0f;

#pragma unroll
  for (int kk = 0; kk < K0 / 32; ++kk) {
    const int off = kk * 32;
    bf16x8 bfr[4];
#pragma unroll
    for (int ct = 0; ct < 4; ++ct)
      bfr[ct] = *reinterpret_cast<const bf16x8*>(w0row[ct] + off);
    bf16x8 afr[2][2];
#pragma unroll
    for (int t = 0; t < 2; ++t)
#pragma unroll
      for (int rt = 0; rt < 2; ++rt) {
        const unsigned short* p =
            Abuf + (t * 32 + rt * 16 + l15) * MID_STRIDE + off + kg * 8;
        bf16x4 lo = *reinterpret_cast<const bf16x4*>(p);
        bf16x4 hi = *reinterpret_cast<const bf16x4*>(p + 4);
        bf16x8 a;
#pragma unroll
        for (int j = 0; j < 4; ++j) {
          a[j] = lo[j];
          a[j + 4] = hi[j];
        }
        afr[t][rt] = a;
      }
#pragma unroll
    for (int t = 0; t < 2; ++t)
#pragma unroll
      for (int rt = 0; rt < 2; ++rt)
#pragma unroll
        for (int ct = 0; ct < 4; ++ct)
          acc0[t][rt][ct] = __builtin_amdgcn_mfma_f32_16x16x32_bf16(
              afr[t][rt], bfr[ct], acc0[t][rt][ct], 0, 0, 0);
  }
  __syncthreads();  // all reads of Abuf done before overwrite

  // ---- Phase 2: epilogue0 -> LDS (mid = relu(. + b0), bf16) ----
#pragma unroll
  for (int t = 0; t < 2; ++t)
#pragma unroll
    for (int ct = 0; ct < 4; ++ct) {
      int col = col0 + ct * 16 + l15;
      float bv = b0[col];
#pragma unroll
      for (int rt = 0; rt < 2; ++rt)
#pragma unroll
        for (int i = 0; i < 4; ++i) {
          int row_l = t * 32 + rt * 16 + kg * 4 + i;
          Abuf[row_l * MID_STRIDE + col] =
              bfbits(fmaxf(acc0[t][rt][ct][i] + bv, 0.0f));
        }
    }
  __syncthreads();

  // ---- Phase 3: GEMM1 (A from LDS, K=256) ----
  const unsigned short* w1row[4];
#pragma unroll
  for (int ct = 0; ct < 4; ++ct)
    w1row[ct] =
        (const unsigned short*)W1 + (size_t)(col0 + ct * 16 + l15) * D_H + kg * 8;

  f32x4 acc1[2][2][4];
#pragma unroll
  for (int t = 0; t < 2; ++t)
#pragma unroll
    for (int rt = 0; rt < 2; ++rt)
#pragma unroll
      for (int ct = 0; ct < 4; ++ct) acc1[t][rt][ct] = 0.0f;

#pragma unroll
  for (int kk = 0; kk < D_H / 32; ++kk) {
    const int off = kk * 32;
    bf16x8 wfr[4];
#pragma unroll
    for (int ct = 0; ct < 4; ++ct)
      wfr[ct] = *reinterpret_cast<const bf16x8*>(w1row[ct] + off);
    bf16x8 afr[2][2];
#pragma unroll
    for (int t = 0; t < 2; ++t)
#pragma unroll
      for (int rt = 0; rt < 2; ++rt) {
        const unsigned short* p =
            Abuf + (t * 32 + rt * 16 + l15) * MID_STRIDE + off + kg * 8;
        bf16x4 lo = *reinterpret_cast<const bf16x4*>(p);
        bf16x4 hi = *reinterpret_cast<const bf16x4*>(p + 4);
        bf16x8 a;
#pragma unroll
        for (int j = 0; j < 4; ++j) {
          a[j] = lo[j];
          a[j + 4] = hi[j];
        }
        afr[t][rt] = a;
      }
#pragma unroll
    for (int t = 0; t < 2; ++t)
#pragma unroll
      for (int rt = 0; rt < 2; ++rt)
#pragma unroll
        for (int ct = 0; ct < 4; ++ct)
          acc1[t][rt][ct] = __builtin_amdgcn_mfma_f32_16x16x32_bf16(
              afr[t][rt], wfr[ct], acc1[t][rt][ct], 0, 0, 0);
  }

  // ---- epilogue1 -> global (relu) ----
#pragma unroll
  for (int t = 0; t < 2; ++t)
#pragma unroll
    for (int ct = 0; ct < 4; ++ct) {
      int col = col0 + ct * 16 + l15;
      float bv = b1[col];
#pragma unroll
      for (int rt = 0; rt < 2; ++rt)
#pragma unroll
        for (int i = 0; i < 4; ++i) {
          int row = row0 + t * 32 + rt * 16 + kg * 4 + i;
          if (row < Nrows) {
            float v = fmaxf(acc1[t][rt][ct][i] + bv, 0.0f);
            if (OUT_BF16)
              ((__hip_bfloat16*)Outp)[(size_t)row * D_H + col] = __float2bfloat16(v);
            else
              ((float*)Outp)[(size_t)row * D_H + col] = v;
          }
        }
    }
}

extern "C" void kernel_launch(void* const* d_in, const int* in_sizes, int n_in,
                              void* d_out, int out_size, void* d_ws, size_t ws_size,
                              hipStream_t stream) {
  const float* x = (const float*)d_in[0];
  const int* ei = (const int*)d_in[1];  // [2, E]: row0 = src, row1 = dst
  const float* eps_all = (const float*)d_in[2];
  const float* w0_l0 = (const float*)d_in[3];
  const float* b0_l0 = (const float*)d_in[4];
  const float* w1_l0 = (const float*)d_in[5];
  const float* b1_l0 = (const float*)d_in[6];
  const float* w0_rest = (const float*)d_in[7];
  const float* b0_rest = (const float*)d_in[8];
  const float* w1_rest = (const float*)d_in[9];
  const float* b1_rest = (const float*)d_in[10];

  const int N = in_sizes[0] / D_IN;  // 50000
  const int E = in_sizes[1] / 2;     // 800000

  char* ws = (char*)d_ws;
  const size_t node_bf = (size_t)N * D_H * sizeof(unsigned short);  // 25.6 MB
  unsigned short* h = (unsigned short*)ws;       // layer outputs (bf16)
  unsigned short* pre = (unsigned short*)(ws + node_bf);
  char* p = ws + 2 * node_bf;
  __hip_bfloat16* wbf = (__hip_bfloat16*)p;
  p += 622592 * sizeof(__hip_bfloat16);
  int* deg = (int*)p;           // [N]
  int* cursor = deg + N;        // [N]
  int* row_start = cursor + N;  // [N]
  int* bsum = row_start + N;    // [64]
  int* csr = bsum + 64;         // [E]

  __hip_bfloat16* w0_l0_bf = wbf;
  __hip_bfloat16* w1_l0_bf = wbf + 32768;
  __hip_bfloat16* w0_rest_bf = wbf + 98304;
  __hip_bfloat16* w1_rest_bf = w0_rest_bf + 262144;

  conv_weights<<<(622592 + 255) / 256, 256, 0, stream>>>(w0_l0, w1_l0, w0_rest,
                                                         w1_rest, wbf);

  // CSR build
  const int nb = (N + 1023) / 1024;  // 49
  zero_ints<<<(2 * N + 255) / 256, 256, 0, stream>>>(deg, 2 * N);  // deg + cursor
  hist_kernel<<<(E + 255) / 256, 256, 0, stream>>>(ei, E, deg);
  block_sums<<<nb, 256, 0, stream>>>(deg, bsum, N);
  scan_bsums<<<1, 64, 0, stream>>>(bsum, nb);
  scan_apply<<<nb, 256, 0, stream>>>(deg, bsum, row_start, N);
  fill_kernel<<<(E + 255) / 256, 256, 0, stream>>>(ei, E, row_start, cursor, csr);

  const int gemmBlocks = (N + 63) / 64;
  const int aggBlocks = (N + 7) / 8;

  for (int layer = 0; layer < NLAYERS; ++layer) {
    const __hip_bfloat16* w0 =
        (layer == 0) ? w0_l0_bf : w0_rest_bf + (size_t)(layer - 1) * 65536;
    const float* b0 = (layer == 0) ? b0_l0 : b0_rest + (size_t)(layer - 1) * 256;
    const __hip_bfloat16* w1 =
        (layer == 0) ? w1_l0_bf : w1_rest_bf + (size_t)(layer - 1) * 65536;
    const float* b1 = (layer == 0) ? b1_l0 : b1_rest + (size_t)(layer - 1) * 256;

    if (layer == 0) {
      aggregate<D_IN, true><<<aggBlocks, 256, 0, stream>>>(
          x, csr, row_start, deg, eps_all, layer, pre, N);
      gin_mlp<D_IN, true><<<gemmBlocks, 256, 0, stream>>>(
          (const __hip_bfloat16*)pre, w0, b0, w1, b1, h, N);
    } else {
      aggregate<D_H, false><<<aggBlocks, 256, 0, stream>>>(
          h, csr, row_start, deg, eps_all, layer, pre, N);
      if (layer == NLAYERS - 1)
        gin_mlp<D_H, false><<<gemmBlocks, 256, 0, stream>>>(
            (const __hip_bfloat16*)pre, w0, b0, w1, b1, d_out, N);
      else
        gin_mlp<D_H, true><<<gemmBlocks, 256, 0, stream>>>(
            (const __hip_bfloat16*)pre, w0, b0, w1, b1, h, N);
    }
  }
}